// Round 3
// baseline (104.708 us; speedup 1.0000x reference)
//
#include <hip/hip_runtime.h>
#include <math.h>

#define B 1024
#define D 128
#define TDIM 1

constexpr float THR   = 0.05f;
constexpr float LAM1f = 1.0f;
constexpr float LAM2f = 0.5f;
constexpr float EPSf  = 1e-8f;

struct SelState {
  unsigned n_pos;
  unsigned prefix;
  unsigned k;
  float    T_eff;
};

// ---- column mean/std (ddof=1) + zero hist/accumulators for this call ----
__global__ void __launch_bounds__(256) col_stats(const float* __restrict__ x,
                                                 float* __restrict__ m,
                                                 float* __restrict__ s,
                                                 unsigned* __restrict__ hist,
                                                 unsigned long long* __restrict__ acc_loss,
                                                 unsigned* __restrict__ acc_cnt,
                                                 unsigned* __restrict__ ticket) {
  int d = blockIdx.x;           // 0..127 (column)
  int t = threadIdx.x;          // 0..255
  // side duty: zero global state used later in the stream (deterministic per call)
  if (d < 8) hist[d * 256 + t] = 0u;
  if (d == 8 && t == 0) { *acc_loss = 0ull; *acc_cnt = 0u; *ticket = 0u; }

  float v[4];
#pragma unroll
  for (int k = 0; k < 4; ++k) v[k] = x[(t + k * 256) * D + d];
  __shared__ float red[256];
  red[t] = v[0] + v[1] + v[2] + v[3];
  __syncthreads();
  for (int o = 128; o > 0; o >>= 1) {
    if (t < o) red[t] += red[t + o];
    __syncthreads();
  }
  __shared__ float mean_sh;
  if (t == 0) mean_sh = red[0] * (1.0f / 1024.0f);
  __syncthreads();
  float mean = mean_sh;
  float sq = 0.f;
#pragma unroll
  for (int k = 0; k < 4; ++k) { float dv = v[k] - mean; sq += dv * dv; }
  __syncthreads();
  red[t] = sq;
  __syncthreads();
  for (int o = 128; o > 0; o >>= 1) {
    if (t < o) red[t] += red[t + o];
    __syncthreads();
  }
  if (t == 0) {
    float var = red[0] * (1.0f / 1023.0f);
    float sd = sqrtf(var);
    if (sd < 1e-6f) sd = 1e-6f;
    m[d] = mean;
    s[d] = sd;
  }
}

// ---- normalize rows; emit xn, z2 (col TDIM), r2o (sum of xn^2 over d!=TDIM) ----
__global__ void __launch_bounds__(128) normalize_rows(const float* __restrict__ x,
                                                      const float* __restrict__ m,
                                                      const float* __restrict__ s,
                                                      float* __restrict__ xn,
                                                      float* __restrict__ z2,
                                                      float* __restrict__ r2o) {
  int i = blockIdx.x;           // row
  int d = threadIdx.x;          // 0..127
  float v = (x[i * D + d] - m[d]) / s[d];
  xn[i * D + d] = v;
  if (d == TDIM) z2[i] = v;
  float c = (d == TDIM) ? 0.f : v * v;
  __shared__ float red[128];
  red[d] = c;
  __syncthreads();
  for (int o = 64; o > 0; o >>= 1) {
    if (d < o) red[d] += red[d + o];
    __syncthreads();
  }
  if (d == 0) r2o[i] = red[0];
}

// ---- radix-select histogram pass over masked d2 values ----
__global__ void __launch_bounds__(256) hist_pass(const float* __restrict__ y,
                                                 const float* __restrict__ z2,
                                                 unsigned* __restrict__ hist,
                                                 const SelState* __restrict__ st,
                                                 int level) {
  __shared__ unsigned lh[2048];
  for (int b = threadIdx.x; b < 2048; b += 256) lh[b] = 0;
  __syncthreads();
  int i = blockIdx.x;
  float yi = y[i], zi = z2[i];
  unsigned pref = st->prefix;
  for (int j = threadIdx.x; j < B; j += 256) {
    if (j == i) continue;
    if (fabsf(yi - y[j]) > THR) continue;
    float dz = zi - z2[j];
    unsigned bits = __float_as_uint(dz * dz);
    if (level == 0) {
      atomicAdd(&lh[bits >> 21], 1u);
    } else if (level == 1) {
      if ((bits >> 21) == pref) atomicAdd(&lh[(bits >> 10) & 0x7FFu], 1u);
    } else {
      if ((bits >> 10) == pref) atomicAdd(&lh[bits & 0x3FFu], 1u);
    }
  }
  __syncthreads();
  for (int b = threadIdx.x; b < 2048; b += 256) {
    unsigned c = lh[b];
    if (c) atomicAdd(&hist[b], c);
  }
}

// ---- parallel scan of histogram: descend one radix level; zero hist after ----
__global__ void __launch_bounds__(256) scan_pass(unsigned* __restrict__ hist,
                                                 SelState* __restrict__ st,
                                                 int level) {
  const int nb  = (level == 2) ? 1024 : 2048;
  const int per = nb >> 8;                     // 8 or 4 buckets/thread
  int t = threadIdx.x;
  unsigned local[8];
  unsigned lsum = 0;
#pragma unroll
  for (int q = 0; q < 8; ++q) {
    unsigned v = (q < per) ? hist[t * per + q] : 0u;
    local[q] = v;
    lsum += v;
  }
  // wave-level inclusive scan of per-thread sums (wave64)
  unsigned incl = lsum;
#pragma unroll
  for (int o = 1; o < 64; o <<= 1) {
    unsigned nbr = __shfl_up(incl, o, 64);
    if ((t & 63) >= o) incl += nbr;
  }
  __shared__ unsigned wsum[4];
  __shared__ unsigned tot_sh;
  if ((t & 63) == 63) wsum[t >> 6] = incl;
  __syncthreads();
  unsigned wpre = 0;
  for (int wv = 0; wv < (t >> 6); ++wv) wpre += wsum[wv];
  incl += wpre;
  unsigned excl = incl - lsum;
  if (t == 255) tot_sh = incl;
  __syncthreads();
  unsigned total = tot_sh;

  bool active = true;
  unsigned kk = 0;
  if (level == 0) {
    if (t == 0) {
      st->n_pos = total;
      if (total == 0) { st->prefix = 0; st->k = 0; st->T_eff = 2.0f; }
    }
    if (total == 0) active = false;
    else kk = (total - 1) >> 1;
  } else {
    if (st->n_pos == 0) active = false;
    else kk = st->k;
  }

  if (active && kk >= excl && kk < incl) {   // exactly one thread
    unsigned cum = excl;
    for (int q = 0; q < per; ++q) {
      if (cum + local[q] > kk) {
        unsigned b = (unsigned)(t * per + q);
        if (level == 0)      { st->prefix = b; st->k = kk - cum; }
        else if (level == 1) { st->prefix = (st->prefix << 11) | b; st->k = kk - cum; }
        else {
          unsigned bits = (st->prefix << 10) | b;
          st->T_eff = fmaxf(__uint_as_float(bits), 1e-6f);
        }
        break;
      }
      cum += local[q];
    }
  }
  __syncthreads();
  for (int b2 = t; b2 < 2048; b2 += 256) hist[b2] = 0;
}

// ---- main pairwise pass + deterministic fused final reduction ----
__global__ void __launch_bounds__(256) pair_main(const float* __restrict__ y,
                                                 const float* __restrict__ z2,
                                                 const float* __restrict__ r2o,
                                                 const float* __restrict__ xn,
                                                 const SelState* __restrict__ st,
                                                 unsigned long long* __restrict__ acc_loss,
                                                 unsigned* __restrict__ acc_cnt,
                                                 unsigned* __restrict__ ticket,
                                                 float* __restrict__ out) {
  int i = blockIdx.x;
  __shared__ float xi[D];
  for (int d = threadIdx.x; d < D; d += 256) xi[d] = xn[i * D + d];
  __syncthreads();
  float yi = y[i], zi = z2[i], ri = r2o[i];
  float invT = 1.0f / st->T_eff;
  float num = 0.f, den1 = 0.f, den2 = 0.f;
  int cnt = 0;
  for (int j = threadIdx.x; j < B; j += 256) {
    if (j == i) continue;
    float zj = z2[j];
    float dz = zi - zj;
    float d2 = dz * dz;
    float K2 = expf(-d2 * invT);
    den1 += K2;
    if (fabsf(yi - y[j]) <= THR) {
      num += K2;
      cnt++;
      const float* xj = xn + j * D;
      float dot = 0.f;
#pragma unroll
      for (int d = 0; d < D; d += 4) {
        float4 a = *(const float4*)(xi + d);
        float4 bb = *(const float4*)(xj + d);
        dot += a.x * bb.x + a.y * bb.y + a.z * bb.z + a.w * bb.w;
      }
      float dot_o = dot - zi * zj;
      float sq = (ri + r2o[j] - 2.f * dot_o) * (1.0f / 127.0f);
      sq = fmaxf(sq, 0.f);
      den2 += expf(-sq * invT);
    }
  }
  __shared__ float rn[256], r1[256], r2s[256];
  __shared__ int rc[256];
  int t = threadIdx.x;
  rn[t] = num; r1[t] = den1; r2s[t] = den2; rc[t] = cnt;
  __syncthreads();
  for (int o = 128; o > 0; o >>= 1) {
    if (t < o) {
      rn[t] += rn[t + o];
      r1[t] += r1[t + o];
      r2s[t] += r2s[t + o];
      rc[t] += rc[t + o];
    }
    __syncthreads();
  }
  if (t == 0) {
    float denom = LAM1f * r1[0] + LAM2f * r2s[0] + EPSf;
    float frac = rn[0] / denom;
    frac = fminf(fmaxf(frac, 1e-12f), 1.0f - 1e-7f);
    if (rc[0] > 0) {
      float lossv = -logf(frac);                       // in (0, 27.7]
      // fixed-point (x 2^32) integer accumulation: bit-deterministic
      unsigned long long fx =
          (unsigned long long)((double)lossv * 4294967296.0);
      atomicAdd(acc_loss, fx);
      atomicAdd(acc_cnt, 1u);
    }
    __threadfence();
    unsigned my = atomicAdd(ticket, 1u);
    if (my == B - 1) {                                  // last block finishes
      __threadfence();
      unsigned long long fl = atomicAdd(acc_loss, 0ull);
      unsigned c = atomicAdd(acc_cnt, 0u);
      float lv = (float)((double)fl * (1.0 / 4294967296.0));
      out[0] = (c > 0) ? lv / (float)c : 0.f;
    }
  }
}

extern "C" void kernel_launch(void* const* d_in, const int* in_sizes, int n_in,
                              void* d_out, int out_size, void* d_ws, size_t ws_size,
                              hipStream_t stream) {
  const float* x = (const float*)d_in[0];   // (1024,128) f32
  const float* y = (const float*)d_in[1];   // (1024,)    f32
  float* out = (float*)d_out;               // scalar f32

  char* w = (char*)d_ws;
  float* m    = (float*)w;            w += 128 * sizeof(float);
  float* s    = (float*)w;            w += 128 * sizeof(float);
  float* xn   = (float*)w;            w += (size_t)B * D * sizeof(float);
  float* z2   = (float*)w;            w += B * sizeof(float);
  float* r2o  = (float*)w;            w += B * sizeof(float);
  unsigned* hist = (unsigned*)w;      w += 2048 * sizeof(unsigned);
  SelState* st = (SelState*)w;        w += 64;
  unsigned long long* acc_loss = (unsigned long long*)w; w += 8;
  unsigned* acc_cnt = (unsigned*)w;   w += 8;
  unsigned* ticket  = (unsigned*)w;   w += 8;

  col_stats<<<D, 256, 0, stream>>>(x, m, s, hist, acc_loss, acc_cnt, ticket);
  normalize_rows<<<B, 128, 0, stream>>>(x, m, s, xn, z2, r2o);

  hist_pass<<<B, 256, 0, stream>>>(y, z2, hist, st, 0);
  scan_pass<<<1, 256, 0, stream>>>(hist, st, 0);
  hist_pass<<<B, 256, 0, stream>>>(y, z2, hist, st, 1);
  scan_pass<<<1, 256, 0, stream>>>(hist, st, 1);
  hist_pass<<<B, 256, 0, stream>>>(y, z2, hist, st, 2);
  scan_pass<<<1, 256, 0, stream>>>(hist, st, 2);

  pair_main<<<B, 256, 0, stream>>>(y, z2, r2o, xn, st,
                                   acc_loss, acc_cnt, ticket, out);
}

// Round 4
// 59.163 us; speedup vs baseline: 1.7698x; 1.7698x over previous
//
#include <hip/hip_runtime.h>
#include <math.h>

#define B 1024
#define D 128
#define TDIM 1

constexpr float THR   = 0.05f;
constexpr float LAM1f = 1.0f;
constexpr float LAM2f = 0.5f;
constexpr float EPSf  = 1e-8f;

// ---- cooperative 256-thread radix-select over a histogram level ----
// Returns bucket containing rank kk (or median rank if kk_in==~0u), the
// remaining rank within that bucket, and the total count. Pure integer ops on
// identical global data -> bit-identical result in every block that calls it.
struct SelOut { unsigned total, bucket, rem; };

__device__ SelOut block_select(const unsigned* __restrict__ h, int nb, unsigned kk_in) {
  int t = threadIdx.x;
  const int per = nb >> 8;                 // 8 (nb=2048) or 4 (nb=1024)
  unsigned local[8];
  unsigned lsum = 0;
#pragma unroll
  for (int q = 0; q < 8; ++q) {
    unsigned v = (q < per) ? h[t * per + q] : 0u;
    local[q] = v; lsum += v;
  }
  unsigned incl = lsum;
#pragma unroll
  for (int o = 1; o < 64; o <<= 1) {
    unsigned nbr = __shfl_up(incl, o, 64);
    if ((t & 63) >= o) incl += nbr;
  }
  __shared__ unsigned sel_wsum[4];
  __shared__ unsigned sel_res[3];
  if ((t & 63) == 63) sel_wsum[t >> 6] = incl;
  __syncthreads();
  unsigned wpre = 0;
  for (int wv = 0; wv < (t >> 6); ++wv) wpre += sel_wsum[wv];
  incl += wpre;
  unsigned excl = incl - lsum;
  if (t == 255) sel_res[0] = incl;
  __syncthreads();
  unsigned total = sel_res[0];
  unsigned kk = (kk_in == 0xFFFFFFFFu) ? ((total ? total - 1u : 0u) >> 1) : kk_in;
  if (total && kk >= excl && kk < incl) {   // exactly one thread
    unsigned cum = excl;
    for (int q = 0; q < per; ++q) {
      if (cum + local[q] > kk) { sel_res[1] = (unsigned)(t * per + q); sel_res[2] = kk - cum; break; }
      cum += local[q];
    }
  }
  __syncthreads();
  SelOut o; o.total = total; o.bucket = sel_res[1]; o.rem = sel_res[2];
  return o;                                 // bucket/rem only valid if total>0
}

// ---- column mean/std (ddof=1) + zero the 3 histogram regions ----
__global__ void __launch_bounds__(256) col_stats(const float* __restrict__ x,
                                                 float* __restrict__ m,
                                                 float* __restrict__ s,
                                                 unsigned* __restrict__ histall) {
  int d = blockIdx.x;           // 0..127 (column)
  int t = threadIdx.x;          // 0..255
  if (d < 20) histall[d * 256 + t] = 0u;   // 5120 u32 = hist0|hist1|hist2

  float v[4];
#pragma unroll
  for (int k = 0; k < 4; ++k) v[k] = x[(t + k * 256) * D + d];
  __shared__ float red[256];
  red[t] = v[0] + v[1] + v[2] + v[3];
  __syncthreads();
  for (int o = 128; o > 0; o >>= 1) {
    if (t < o) red[t] += red[t + o];
    __syncthreads();
  }
  __shared__ float mean_sh;
  if (t == 0) mean_sh = red[0] * (1.0f / 1024.0f);
  __syncthreads();
  float mean = mean_sh;
  float sq = 0.f;
#pragma unroll
  for (int k = 0; k < 4; ++k) { float dv = v[k] - mean; sq += dv * dv; }
  __syncthreads();
  red[t] = sq;
  __syncthreads();
  for (int o = 128; o > 0; o >>= 1) {
    if (t < o) red[t] += red[t + o];
    __syncthreads();
  }
  if (t == 0) {
    float var = red[0] * (1.0f / 1023.0f);
    float sd = sqrtf(var);
    if (sd < 1e-6f) sd = 1e-6f;
    m[d] = mean;
    s[d] = sd;
  }
}

// ---- normalize rows; emit xn, z2 (col TDIM), r2o (sum of xn^2 over d!=TDIM) ----
__global__ void __launch_bounds__(128) normalize_rows(const float* __restrict__ x,
                                                      const float* __restrict__ m,
                                                      const float* __restrict__ s,
                                                      float* __restrict__ xn,
                                                      float* __restrict__ z2,
                                                      float* __restrict__ r2o) {
  int i = blockIdx.x;
  int d = threadIdx.x;
  float v = (x[i * D + d] - m[d]) / s[d];
  xn[i * D + d] = v;
  if (d == TDIM) z2[i] = v;
  float c = (d == TDIM) ? 0.f : v * v;
  __shared__ float red[128];
  red[d] = c;
  __syncthreads();
  for (int o = 64; o > 0; o >>= 1) {
    if (d < o) red[d] += red[d + o];
    __syncthreads();
  }
  if (d == 0) r2o[i] = red[0];
}

// ---- radix level 0: 11-bit msb histogram of masked d2 (4 rows per block) ----
__global__ void __launch_bounds__(256) hist_l0(const float* __restrict__ y,
                                               const float* __restrict__ z2,
                                               unsigned* __restrict__ g) {
  __shared__ unsigned lh[2048];
  int t = threadIdx.x;
  for (int b = t; b < 2048; b += 256) lh[b] = 0;
  __syncthreads();
  for (int r = 0; r < 4; ++r) {
    int i = blockIdx.x * 4 + r;
    float yi = y[i], zi = z2[i];
    for (int j = t; j < B; j += 256) {
      if (j == i) continue;
      if (fabsf(yi - y[j]) > THR) continue;
      float dz = zi - z2[j];
      atomicAdd(&lh[__float_as_uint(dz * dz) >> 21], 1u);
    }
  }
  __syncthreads();
  for (int b = t; b < 2048; b += 256) { unsigned c = lh[b]; if (c) atomicAdd(&g[b], c); }
}

// ---- radix level 1: redundant scan of level 0, histogram of mid 11 bits ----
__global__ void __launch_bounds__(256) hist_l1(const float* __restrict__ y,
                                               const float* __restrict__ z2,
                                               const unsigned* __restrict__ h0,
                                               unsigned* __restrict__ g) {
  SelOut s0 = block_select(h0, 2048, 0xFFFFFFFFu);
  if (s0.total == 0) return;
  unsigned p0 = s0.bucket;
  __shared__ unsigned lh[2048];
  int t = threadIdx.x;
  for (int b = t; b < 2048; b += 256) lh[b] = 0;
  __syncthreads();
  for (int r = 0; r < 4; ++r) {
    int i = blockIdx.x * 4 + r;
    float yi = y[i], zi = z2[i];
    for (int j = t; j < B; j += 256) {
      if (j == i) continue;
      if (fabsf(yi - y[j]) > THR) continue;
      float dz = zi - z2[j];
      unsigned bits = __float_as_uint(dz * dz);
      if ((bits >> 21) == p0) atomicAdd(&lh[(bits >> 10) & 0x7FFu], 1u);
    }
  }
  __syncthreads();
  for (int b = t; b < 2048; b += 256) { unsigned c = lh[b]; if (c) atomicAdd(&g[b], c); }
}

// ---- radix level 2: redundant scans of levels 0,1; histogram of low 10 bits ----
__global__ void __launch_bounds__(256) hist_l2(const float* __restrict__ y,
                                               const float* __restrict__ z2,
                                               const unsigned* __restrict__ h0,
                                               const unsigned* __restrict__ h1,
                                               unsigned* __restrict__ g) {
  SelOut s0 = block_select(h0, 2048, 0xFFFFFFFFu);
  if (s0.total == 0) return;
  SelOut s1 = block_select(h1, 2048, s0.rem);
  unsigned pref = (s0.bucket << 11) | s1.bucket;
  __shared__ unsigned lh[1024];
  int t = threadIdx.x;
  for (int b = t; b < 1024; b += 256) lh[b] = 0;
  __syncthreads();
  for (int r = 0; r < 4; ++r) {
    int i = blockIdx.x * 4 + r;
    float yi = y[i], zi = z2[i];
    for (int j = t; j < B; j += 256) {
      if (j == i) continue;
      if (fabsf(yi - y[j]) > THR) continue;
      float dz = zi - z2[j];
      unsigned bits = __float_as_uint(dz * dz);
      if ((bits >> 10) == pref) atomicAdd(&lh[bits & 0x3FFu], 1u);
    }
  }
  __syncthreads();
  for (int b = t; b < 1024; b += 256) { unsigned c = lh[b]; if (c) atomicAdd(&g[b], c); }
}

// ---- main pairwise pass (redundant final scan; ballot-compacted j list) ----
__global__ void __launch_bounds__(256) pair_main(const float* __restrict__ y,
                                                 const float* __restrict__ z2,
                                                 const float* __restrict__ r2o,
                                                 const float* __restrict__ xn,
                                                 const unsigned* __restrict__ h0,
                                                 const unsigned* __restrict__ h1,
                                                 const unsigned* __restrict__ h2,
                                                 float* __restrict__ loss_i,
                                                 unsigned* __restrict__ haspos_i) {
  int t = threadIdx.x;
  int i = blockIdx.x;

  SelOut s0 = block_select(h0, 2048, 0xFFFFFFFFu);
  float T;
  if (s0.total == 0) {
    T = 2.0f;
  } else {
    SelOut s1 = block_select(h1, 2048, s0.rem);
    SelOut s2 = block_select(h2, 1024, s1.rem);
    unsigned bits = (s0.bucket << 21) | (s1.bucket << 10) | s2.bucket;
    T = fmaxf(__uint_as_float(bits), 1e-6f);
  }
  float invT = 1.0f / T;

  __shared__ float xi[D];
  for (int d = t; d < D; d += 256) xi[d] = xn[i * D + d];

  float yi = y[i], zi = z2[i], ri = r2o[i];

  // den1 over ALL j (j==i contributes exp(0)=1 exactly; removed after reduce)
  float4 zz = *(const float4*)(z2 + t * 4);
  float e0 = zi - zz.x, e1 = zi - zz.y, e2 = zi - zz.z, e3 = zi - zz.w;
  float den1 = __expf(-e0 * e0 * invT) + __expf(-e1 * e1 * invT)
             + __expf(-e2 * e2 * invT) + __expf(-e3 * e3 * invT);

  // deterministic ballot-compaction of same-age neighbors
  __shared__ unsigned short jlist[B];
  __shared__ unsigned wcnt_sh[4];
  unsigned base = 0;
  int lane = t & 63, wv = t >> 6;
  for (int rnd = 0; rnd < 4; ++rnd) {
    int j = rnd * 256 + t;
    bool ok = (j != i) && (fabsf(yi - y[j]) <= THR);
    unsigned long long mk = __ballot(ok);
    if (lane == 0) wcnt_sh[wv] = (unsigned)__popcll(mk);
    __syncthreads();
    unsigned pre = base;
    for (int w = 0; w < wv; ++w) pre += wcnt_sh[w];
    if (ok) {
      unsigned mypos = (unsigned)__popcll(mk & ((1ull << lane) - 1ull));
      jlist[pre + mypos] = (unsigned short)j;
    }
    base += wcnt_sh[0] + wcnt_sh[1] + wcnt_sh[2] + wcnt_sh[3];
    __syncthreads();
  }
  unsigned cnt = base;   // block-uniform, deterministic (sorted by j)

  float num = 0.f, den2 = 0.f;
  for (unsigned q = t; q < cnt; q += 256) {
    int j = jlist[q];
    float zj = z2[j];
    float dz = zi - zj;
    num += __expf(-dz * dz * invT);
    const float* xj = xn + j * D;
    float dot = 0.f;
#pragma unroll
    for (int d = 0; d < D; d += 4) {
      float4 a  = *(const float4*)(xi + d);
      float4 bb = *(const float4*)(xj + d);
      dot += a.x * bb.x + a.y * bb.y + a.z * bb.z + a.w * bb.w;
    }
    float dot_o = dot - zi * zj;
    float sq = fmaxf((ri + r2o[j] - 2.f * dot_o) * (1.0f / 127.0f), 0.f);
    den2 += __expf(-sq * invT);
  }

  __shared__ float rn[256], r1[256], r2s[256];
  rn[t] = num; r1[t] = den1; r2s[t] = den2;
  __syncthreads();
  for (int o = 128; o > 0; o >>= 1) {
    if (t < o) { rn[t] += rn[t + o]; r1[t] += r1[t + o]; r2s[t] += r2s[t + o]; }
    __syncthreads();
  }
  if (t == 0) {
    float den1t = r1[0] - 1.0f;               // remove j==i term
    float denom = LAM1f * den1t + LAM2f * r2s[0] + EPSf;
    float frac = fminf(fmaxf(rn[0] / denom, 1e-12f), 1.0f - 1e-7f);
    loss_i[i]   = (cnt > 0) ? -__logf(frac) : 0.f;
    haspos_i[i] = (cnt > 0) ? 1u : 0u;
  }
}

// ---- final deterministic reduction to scalar loss ----
__global__ void __launch_bounds__(256) finalize(const float* __restrict__ loss_i,
                                                const unsigned* __restrict__ haspos_i,
                                                float* __restrict__ out) {
  __shared__ float rs[256];
  __shared__ unsigned rcnt[256];
  int t = threadIdx.x;
  float sv = 0.f;
  unsigned c = 0;
  for (int i = t; i < B; i += 256) { sv += loss_i[i]; c += haspos_i[i]; }
  rs[t] = sv; rcnt[t] = c;
  __syncthreads();
  for (int o = 128; o > 0; o >>= 1) {
    if (t < o) { rs[t] += rs[t + o]; rcnt[t] += rcnt[t + o]; }
    __syncthreads();
  }
  if (t == 0) out[0] = (rcnt[0] > 0) ? rs[0] / (float)rcnt[0] : 0.f;
}

extern "C" void kernel_launch(void* const* d_in, const int* in_sizes, int n_in,
                              void* d_out, int out_size, void* d_ws, size_t ws_size,
                              hipStream_t stream) {
  const float* x = (const float*)d_in[0];   // (1024,128) f32
  const float* y = (const float*)d_in[1];   // (1024,)    f32
  float* out = (float*)d_out;               // scalar f32

  char* w = (char*)d_ws;
  float* m    = (float*)w;            w += 128 * sizeof(float);
  float* s    = (float*)w;            w += 128 * sizeof(float);
  float* xn   = (float*)w;            w += (size_t)B * D * sizeof(float);
  float* z2   = (float*)w;            w += B * sizeof(float);
  float* r2o  = (float*)w;            w += B * sizeof(float);
  unsigned* hist0 = (unsigned*)w;     w += 2048 * sizeof(unsigned);
  unsigned* hist1 = (unsigned*)w;     w += 2048 * sizeof(unsigned);
  unsigned* hist2 = (unsigned*)w;     w += 1024 * sizeof(unsigned);
  float* loss_i = (float*)w;          w += B * sizeof(float);
  unsigned* haspos_i = (unsigned*)w;  w += B * sizeof(unsigned);

  col_stats<<<D, 256, 0, stream>>>(x, m, s, hist0);   // hist0..2 contiguous
  normalize_rows<<<B, 128, 0, stream>>>(x, m, s, xn, z2, r2o);

  hist_l0<<<B / 4, 256, 0, stream>>>(y, z2, hist0);
  hist_l1<<<B / 4, 256, 0, stream>>>(y, z2, hist0, hist1);
  hist_l2<<<B / 4, 256, 0, stream>>>(y, z2, hist0, hist1, hist2);

  pair_main<<<B, 256, 0, stream>>>(y, z2, r2o, xn, hist0, hist1, hist2,
                                   loss_i, haspos_i);
  finalize<<<1, 256, 0, stream>>>(loss_i, haspos_i, out);
}